// Round 1
// baseline (160.780 us; speedup 1.0000x reference)
//
#include <hip/hip_runtime.h>

#define RULES 512
#define VOCAB 128000
#define NB 64

typedef float f32x4 __attribute__((ext_vector_type(4)));

// ws layout: pen f32[VOCAB] | masks u32[16] | gates f32[RULES]

// --- K0: zero pen + masks, precompute 0.5*sigmoid(gate_logits) table ---
__global__ void __launch_bounds__(256) init_kernel(
    const float* __restrict__ gate_logits, float* __restrict__ pen,
    unsigned* __restrict__ masks, float* __restrict__ gates) {
    int t = threadIdx.x, b = blockIdx.x;
    if (b < VOCAB / 1024) {
        *(f32x4*)(pen + b * 1024 + t * 4) = (f32x4){0.f, 0.f, 0.f, 0.f};
    } else {
        if (t < 16) masks[t] = 0u;
        float x0 = gate_logits[t], x1 = gate_logits[t + 256];
        gates[t]       = 0.5f / (1.f + expf(-x0));
        gates[t + 256] = 0.5f / (1.f + expf(-x1));
    }
}

// --- K1: single-pass scatter, HW f32 global atomics into pen[V] ---
__global__ void __launch_bounds__(256) scatter_kernel(
    const int* __restrict__ rule_ids, const int* __restrict__ token_ids,
    const float* __restrict__ gates, float* __restrict__ pen,
    unsigned* __restrict__ masks, int E) {
    __shared__ float s_g[RULES];
    __shared__ unsigned char s_f[RULES];
    int t = threadIdx.x;
    s_g[t] = gates[t];
    s_g[t + 256] = gates[t + 256];
    if (t < RULES / 4) ((unsigned*)s_f)[t] = 0u;
    __syncthreads();

    const int stride = gridDim.x * 256 * 4;
    for (int base = (blockIdx.x * 256 + t) * 4; base + 4 <= E; base += stride) {
        int4 tt = *(const int4*)(token_ids + base);
        int4 rr = *(const int4*)(rule_ids + base);
        unsafeAtomicAdd(&pen[tt.x], s_g[rr.x]); s_f[rr.x] = 1;
        unsafeAtomicAdd(&pen[tt.y], s_g[rr.y]); s_f[rr.y] = 1;
        unsafeAtomicAdd(&pen[tt.z], s_g[rr.z]); s_f[rr.z] = 1;
        unsafeAtomicAdd(&pen[tt.w], s_g[rr.w]); s_f[rr.w] = 1;
    }
    if (blockIdx.x == 0 && t == 0) {       // scalar tail (E % 4)
        for (int e = E & ~3; e < E; ++e) {
            unsafeAtomicAdd(&pen[token_ids[e]], s_g[rule_ids[e]]);
            s_f[rule_ids[e]] = 1;
        }
    }
    __syncthreads();

    if (t < 16) {                          // 512 firing bytes -> 16 u32, OR in
        const unsigned* w = (const unsigned*)s_f + t * 8;
        unsigned m = 0;
#pragma unroll
        for (int k = 0; k < 8; ++k) {
            unsigned d = w[k];
            if (d & 0x000000FFu) m |= 1u << (k * 4 + 0);
            if (d & 0x0000FF00u) m |= 1u << (k * 4 + 1);
            if (d & 0x00FF0000u) m |= 1u << (k * 4 + 2);
            if (d & 0xFF000000u) m |= 1u << (k * 4 + 3);
        }
        if (m) atomicOr(&masks[t], m);
    }
}

// --- K2: pure stream. grid (125, 8): block owns 1024 cols x 8 rows. ---
__global__ void __launch_bounds__(256) fused_kernel(
    const float* __restrict__ pen, const unsigned* __restrict__ masks,
    const float* __restrict__ gate_logits, const float* __restrict__ logits,
    float* __restrict__ out_mod, float* __restrict__ out_pen,
    float* __restrict__ out_loss) {
    __shared__ float s_pen[1032];          // 1024 cols + 4 halo (padded)
    int t = threadIdx.x, bx = blockIdx.x, by = blockIdx.y;
    int c0 = bx << 10;
    *(f32x4*)(s_pen + t * 4) = *(const f32x4*)(pen + c0 + t * 4);
    if (t == 0) {
#pragma unroll
        for (int i = 0; i < 4; ++i) {      // halo; wrap = next pen-row's head
            int gc = c0 + 1024 + i; if (gc >= VOCAB) gc -= VOCAB;
            s_pen[1024 + i] = pen[gc];
        }
    }
    __syncthreads();

    // --- loss + pen-region head: block (0,0) only (block-uniform branch) ---
    if (bx == 0 && by == 0) {
        __shared__ float sg[4];
        float gf = 0.f;
#pragma unroll
        for (int k = 0; k < 2; ++k) {
            int ru = t + k * 256;
            if ((masks[ru >> 5] >> (ru & 31)) & 1u)
                gf += 1.f / (1.f + expf(-gate_logits[ru]));
        }
        for (int off = 32; off > 0; off >>= 1) gf += __shfl_down(gf, off, 64);
        if ((t & 63) == 0) sg[t >> 6] = gf;
        __syncthreads();
        if (t == 0) {
            float tf = 0.f;
#pragma unroll
            for (int i = 0; i < 16; ++i) tf += (float)__popc(masks[i]);
            *out_loss = -(sg[0] + sg[1] + sg[2] + sg[3]) / fmaxf(tf, 1.f);
            out_pen[0] = s_pen[0]; out_pen[1] = s_pen[1]; out_pen[2] = s_pen[2];
        }
    }

    f32x4 p0 = *(const f32x4*)(s_pen + t * 4);
    f32x4 pn = *(const f32x4*)(s_pen + t * 4 + 4);
    f32x4 ps = {p0.w, pn.x, pn.y, pn.z}; // shifted window for +3-offset store
    size_t col = (size_t)c0 + t * 4;
    bool lastcol = (bx == VOCAB / 1024 - 1) && (t == 255);
#pragma unroll
    for (int i = 0; i < 8; ++i) {
        int b = (by << 3) + i;
        size_t base = (size_t)b * VOCAB + col;
        f32x4 l = __builtin_nontemporal_load((const f32x4*)(logits + base));
        __builtin_nontemporal_store(l - p0, (f32x4*)(out_mod + base));
        if (lastcol && b == NB - 1) {
            out_pen[base + 3] = p0.w;      // final pen element, no overrun
        } else {
            // out_pen + base + 3 == out + BV + base + 4 -> 16B aligned
            __builtin_nontemporal_store(ps, (f32x4*)(out_pen + base + 3));
        }
    }
}

extern "C" void kernel_launch(void* const* d_in, const int* in_sizes, int n_in,
                              void* d_out, int out_size, void* d_ws, size_t ws_size,
                              hipStream_t stream) {
    const float* logits      = (const float*)d_in[0];
    const float* gate_logits = (const float*)d_in[1];
    const int*   rule_ids    = (const int*)d_in[2];
    const int*   token_ids   = (const int*)d_in[3];
    float* out = (float*)d_out;

    const int E = in_sizes[2];             // 1,000,000
    const size_t BV = (size_t)NB * VOCAB;

    float*    pen   = (float*)d_ws;
    unsigned* masks = (unsigned*)(pen + VOCAB);
    float*    gates = (float*)(pen + VOCAB + 16);

    init_kernel<<<VOCAB / 1024 + 1, 256, 0, stream>>>(gate_logits, pen, masks, gates);
    scatter_kernel<<<1024, 256, 0, stream>>>(rule_ids, token_ids, gates, pen, masks, E);
    fused_kernel<<<dim3(VOCAB / 1024, NB / 8), 256, 0, stream>>>(
        pen, masks, gate_logits, logits, out, out + BV + 1, out + BV);
}

// Round 2
// 122.279 us; speedup vs baseline: 1.3149x; 1.3149x over previous
//
#include <hip/hip_runtime.h>

#define PENALTY_LAMBDA 0.5f
#define RULES 512
#define NR 4            // token ranges
#define RS 32000        // tokens per range (NR*RS == VOCAB)
#define VOCAB 128000
#define G 64            // scatter blocks per range
#define NB 64           // batch rows
#define CH 500          // pen floats per fused-kernel chunk (256 chunks)
#define CJ 125          // f32x4 per chunk

typedef float    f32x4 __attribute__((ext_vector_type(4)));
typedef _Float16 f16x4 __attribute__((ext_vector_type(4)));

// ws layout: partials[NR][G][RS] (fp16) | masks[G][16] (u32)

// --- K1: LDS-histogram scatter, gates fused. grid=(G, NR) x 1024 ---
// 1024 threads (vs 512): LDS caps us at 1 block/CU either way, but this
// doubles resident waves 8->16 per CU (25%->50% occ) for latency hiding.
__global__ void __launch_bounds__(1024) scatter_kernel(
    const int* __restrict__ rule_ids, const int* __restrict__ token_ids,
    const float* __restrict__ gate_logits, _Float16* __restrict__ partials,
    unsigned* __restrict__ masks, int E) {
    __shared__ __align__(16) float hist[RS];
    __shared__ float s_g[RULES];
    __shared__ unsigned char s_f[RULES];
    int t = threadIdx.x;
    int g = blockIdx.x;    // 0..G-1
    int r = blockIdx.y;    // 0..NR-1
    for (int i = t * 4; i < RS; i += 1024 * 4)
        *(f32x4*)(hist + i) = (f32x4){0.f, 0.f, 0.f, 0.f};
    if (t < RULES) {
        float x = gate_logits[t];
        s_g[t] = PENALTY_LAMBDA / (1.0f + expf(-x));   // 0.5*sigmoid
    }
    if (t >= 512 && t < 512 + RULES / 4) ((unsigned*)s_f)[t - 512] = 0u;
    __syncthreads();

    const int lo = r * RS;
    const int stride = G * 1024 * 4;
    for (int base = (g * 1024 + t) * 4; base + 4 <= E; base += stride) {
        int4 tt = *(const int4*)(token_ids + base);
        int4 rr = *(const int4*)(rule_ids + base);
        int ts[4] = {tt.x, tt.y, tt.z, tt.w};
        int rv[4] = {rr.x, rr.y, rr.z, rr.w};
#pragma unroll
        for (int k = 0; k < 4; ++k) {
            int tok = ts[k] - lo;
            if ((unsigned)tok < (unsigned)RS) atomicAdd(&hist[tok], s_g[rv[k]]);
            if (r == 0) s_f[rv[k]] = 1;
        }
    }
    if (g == 0 && t == 0) {             // scalar tail (E % 4)
        for (int e = E & ~3; e < E; ++e) {
            int tok = token_ids[e] - lo; int ru = rule_ids[e];
            if ((unsigned)tok < (unsigned)RS) atomicAdd(&hist[tok], s_g[ru]);
            if (r == 0) s_f[ru] = 1;
        }
    }
    __syncthreads();

    // stream partial histogram out as fp16 (halves IC round-trip traffic)
    _Float16* dst = partials + ((size_t)r * G + g) * RS;
    for (int i = t * 4; i < RS; i += 1024 * 4) {
        f32x4 s = *(const f32x4*)(&hist[i]);
        f16x4 h = {(_Float16)s.x, (_Float16)s.y, (_Float16)s.z, (_Float16)s.w};
        *(f16x4*)(dst + i) = h;
    }

    // firing bitmask: per-block plain stores (no init, no global atomics)
    if (r == 0 && t < 16) {
        const unsigned* w = (const unsigned*)s_f + t * 8;
        unsigned m = 0;
#pragma unroll
        for (int k = 0; k < 8; ++k) {
            unsigned d = w[k];
            if (d & 0x000000FFu) m |= 1u << (k * 4 + 0);
            if (d & 0x0000FF00u) m |= 1u << (k * 4 + 1);
            if (d & 0x00FF0000u) m |= 1u << (k * 4 + 2);
            if (d & 0xFF000000u) m |= 1u << (k * 4 + 3);
        }
        masks[g * 16 + t] = m;
    }
}

// --- K2: fused reduce + loss + broadcast. 256 persistent blocks; block
// `chunk` owns pen columns [chunk*500, chunk*500+500). ---
__global__ void __launch_bounds__(512) fused_kernel(
    const _Float16* __restrict__ partials, const unsigned* __restrict__ masks,
    const float* __restrict__ gate_logits, const float* __restrict__ logits,
    float* __restrict__ out_mod, float* __restrict__ out_pen,
    float* __restrict__ out_loss) {
    __shared__ float s_pc[CH + 4];         // pen chunk + 4 lookahead floats
    __shared__ f32x4 s_part[4][CJ + 1];    // per-ty partial sums
    int t = threadIdx.x;
    int tx = t & 127, ty = t >> 7;         // 128 x 4
    int chunk = blockIdx.x;                // 0..255
    int c0 = chunk * CH;
    int r = c0 / RS;                       // 64 chunks per range; never crosses
    int bin = c0 - r * RS;

    // --- phase A: pen chunk = sum over G fp16 partials (each ty sums 16) ---
    {
        if (tx < CJ) {
            f32x4 acc = {0.f, 0.f, 0.f, 0.f};
            const _Float16* bp = partials + ((size_t)r * G + ty * 16) * RS
                               + bin + tx * 4;
#pragma unroll 4
            for (int g = 0; g < 16; ++g) {
                f16x4 h = *(const f16x4*)(bp + (size_t)g * RS);
                acc += (f32x4){(float)h.x, (float)h.y, (float)h.z, (float)h.w};
            }
            s_part[ty][tx] = acc;
        } else if (tx == 127) {
            // 4 lookahead bins (c0+500 .. c0+503), may cross range / wrap
            f32x4 e = {0.f, 0.f, 0.f, 0.f};
            for (int i = 0; i < 4; ++i) {
                int gb = c0 + CH + i; if (gb >= VOCAB) gb -= VOCAB;
                int r2 = gb / RS, b2 = gb - r2 * RS;
                const _Float16* bp2 = partials + ((size_t)r2 * G + ty * 16) * RS + b2;
                float s = 0.f;
                for (int g = 0; g < 16; ++g) s += (float)bp2[(size_t)g * RS];
                ((float*)&e)[i] = s;
            }
            s_part[ty][CJ] = e;
        }
    }
    __syncthreads();
    if (t < CJ + 1) {
        f32x4 s = s_part[0][t] + s_part[1][t] + s_part[2][t] + s_part[3][t];
        *(f32x4*)(s_pc + t * 4) = s;
    }
    __syncthreads();

    // --- loss: chunk 0 only (block-uniform) ---
    if (chunk == 0) {
        __shared__ unsigned s_mask[16];
        __shared__ float sg[8], sf[8];
        if (t < 16) {
            unsigned m = 0;
            for (int g = 0; g < G; ++g) m |= masks[g * 16 + t];
            s_mask[t] = m;
        }
        __syncthreads();
        float f = ((s_mask[t >> 5] >> (t & 31)) & 1u) ? 1.f : 0.f;
        float gf = f / (1.f + expf(-gate_logits[t]));   // t < 512 == RULES
        for (int off = 32; off > 0; off >>= 1) {
            gf += __shfl_down(gf, off, 64);
            f  += __shfl_down(f,  off, 64);
        }
        if ((t & 63) == 0) { sg[t >> 6] = gf; sf[t >> 6] = f; }
        __syncthreads();
        if (t == 0) {
            float tg = 0.f, tf = 0.f;
            for (int w = 0; w < 8; ++w) { tg += sg[w]; tf += sf[w]; }
            *out_loss = -tg / fmaxf(tf, 1.0f);
            // head of flat pen region (out_pen == out + BV + 1)
            out_pen[0] = s_pc[0];
            out_pen[1] = s_pc[1];
            out_pen[2] = s_pc[2];
        }
    }

    // --- phase B: stream 64 rows, 4 in flight (ty), 125 f32x4 columns (tx) ---
    if (tx >= CJ) return;
    f32x4 p0 = *(const f32x4*)(s_pc + tx * 4);
    f32x4 ps = {s_pc[tx * 4 + 3], s_pc[tx * 4 + 4],
                s_pc[tx * 4 + 5], s_pc[tx * 4 + 6]};
    bool glast = (chunk == 255 && tx == CJ - 1);
    size_t col = (size_t)c0 + tx * 4;
#pragma unroll 4
    for (int ib = 0; ib < NB / 4; ++ib) {
        int b = ib * 4 + ty;
        size_t base = (size_t)b * VOCAB + col;
        f32x4 l = __builtin_nontemporal_load((const f32x4*)(logits + base));
        __builtin_nontemporal_store(l - p0, (f32x4*)(out_mod + base));
        if (glast && b == NB - 1) {
            out_pen[base + 3] = p0.w;      // final element, no overrun
        } else {
            // offset in out: BV+1 + b*V + 4j+3 == 0 (mod 4) -> 16B aligned
            __builtin_nontemporal_store(ps, (f32x4*)(out_pen + base + 3));
        }
    }
}

extern "C" void kernel_launch(void* const* d_in, const int* in_sizes, int n_in,
                              void* d_out, int out_size, void* d_ws, size_t ws_size,
                              hipStream_t stream) {
    const float* logits      = (const float*)d_in[0];
    const float* gate_logits = (const float*)d_in[1];
    const int*   rule_ids    = (const int*)d_in[2];
    const int*   token_ids   = (const int*)d_in[3];
    float* out = (float*)d_out;

    const int E = in_sizes[2];           // 1,000,000
    const size_t BV = (size_t)NB * VOCAB;

    _Float16* partials = (_Float16*)d_ws;
    unsigned* masks    = (unsigned*)(partials + (size_t)NR * G * RS);

    scatter_kernel<<<dim3(G, NR), 1024, 0, stream>>>(
        rule_ids, token_ids, gate_logits, partials, masks, E);

    fused_kernel<<<VOCAB / CH, 512, 0, stream>>>(
        partials, masks, gate_logits, logits,
        out, out + BV + 1, out + BV);
}